// Round 8
// baseline (165.127 us; speedup 1.0000x reference)
//
#include <hip/hip_runtime.h>
#include <hip/hip_bf16.h>

#define IMG 256
#define TS 20

typedef unsigned short u16;
typedef __bf16 bf16x8 __attribute__((ext_vector_type(8)));
typedef float f32x4 __attribute__((ext_vector_type(4)));
typedef unsigned short ushort8 __attribute__((ext_vector_type(8)));

__device__ __forceinline__ float cc1f(float x) {
    const float A = -0.75f;
    return ((A + 2.0f) * x - (A + 3.0f)) * x * x + 1.0f;
}
__device__ __forceinline__ float cc2f(float x) {
    const float A = -0.75f;
    return ((A * x - 5.0f * A) * x + 8.0f * A) * x - 4.0f * A;
}

// fp32 -> bf16 round-to-nearest-even, bit form
__device__ __forceinline__ u16 f2bf(float f) {
    unsigned u = __float_as_uint(f);
    u = u + 0x7fffu + ((u >> 16) & 1u);
    return (u16)(u >> 16);
}

// ---------------------------------------------------------------------------
// build_P2: P_0 = I; P_{i+1} = (N·B)_i · P_i  (row-gather, 4 nnz/row).
// Column-sliced: 32 blocks × 8 columns; 256 threads = one thread per row.
// (verified R4/R5, ~2-4 µs)
// ---------------------------------------------------------------------------
#define BPC 8
#define BPS 12
__global__ __launch_bounds__(256) void build_P2(u16* __restrict__ Pbf) {
    __shared__ __align__(16) float buf[2][IMG][BPS];
    const int col0 = blockIdx.x * BPC;
    const int o = threadIdx.x;

    f32x4 n0 = (f32x4){0.f, 0.f, 0.f, 0.f};
    f32x4 n1 = (f32x4){0.f, 0.f, 0.f, 0.f};
    if (o >= col0 && o < col0 + 4) n0[o - col0] = 1.0f;
    if (o >= col0 + 4 && o < col0 + 8) n1[o - col0 - 4] = 1.0f;
    *(f32x4*)&buf[0][o][0] = n0;
    *(f32x4*)&buf[0][o][4] = n1;
    {
        ushort8 pk;
#pragma unroll
        for (int c = 0; c < 4; ++c) pk[c] = f2bf(n0[c]);
#pragma unroll
        for (int c = 0; c < 4; ++c) pk[4 + c] = f2bf(n1[c]);
        *(ushort8*)(Pbf + (size_t)o * IMG + col0) = pk;
    }

    int cur = 0;
#pragma unroll
    for (int i = 0; i < TS - 1; ++i) {
        const int s = IMG - i;
        float xs = (o + 0.5f) * (float)s * (1.0f / 256.0f);
        int j = (int)xs;
        if (j > s - 1) j = s - 1;
        float x = (j + 0.5f) * (256.0f / (float)s) - 0.5f;
        float fl = floorf(x);
        int i0 = (int)fl;
        float tt = x - fl;
        float w[4] = {cc2f(tt + 1.0f), cc1f(tt), cc1f(1.0f - tt), cc2f(2.0f - tt)};
        int c[4];
#pragma unroll
        for (int k = 0; k < 4; ++k) c[k] = min(max(i0 - 1 + k, 0), IMG - 1);

        __syncthreads();
        f32x4 a0 = (f32x4){0.f, 0.f, 0.f, 0.f};
        f32x4 a1 = (f32x4){0.f, 0.f, 0.f, 0.f};
#pragma unroll
        for (int k = 0; k < 4; ++k) {
            const float wk = w[k];
            a0 += wk * *(const f32x4*)&buf[cur][c[k]][0];
            a1 += wk * *(const f32x4*)&buf[cur][c[k]][4];
        }
        const int nxt = cur ^ 1;
        *(f32x4*)&buf[nxt][o][0] = a0;
        *(f32x4*)&buf[nxt][o][4] = a1;

        ushort8 pk;
#pragma unroll
        for (int cc = 0; cc < 4; ++cc) pk[cc] = f2bf(a0[cc]);
#pragma unroll
        for (int cc = 0; cc < 4; ++cc) pk[4 + cc] = f2bf(a1[cc]);
        *(ushort8*)(Pbf + ((size_t)(i + 1) * IMG + o) * IMG + col0) = pk;
        cur = nxt;
    }
}

// ---------------------------------------------------------------------------
// gemm_px2: C[m,n] = sum_k A[m,k] * Bt[n,k], A = P[t[b]] (both modes).
// MODE 0 (gemm1): Bt = X[bc] fp32 (cvt on stage), C = Z[bc] bf16
// MODE 1 (gemm2): Bt = Z[bc] bf16,               C = out[bc] fp32
// 128x128 tile, 4 waves x (64x64), BK=64, mfma_f32_16x16x32_bf16.
// T14 async-stage pipeline: fetch kt+1 into REGISTERS before the MFMA phase
// of kt; commit regs->LDS after the barrier. Global latency hides under MFMA.
// grid(192,4): an image's 4 tile-blocks land on one XCD (L2-local re-reads).
// ---------------------------------------------------------------------------
template <int MODE>
__global__ __launch_bounds__(256) void gemm_px2(const u16* __restrict__ Pbf,
                                                const void* __restrict__ BtSrc,
                                                void* __restrict__ Cout,
                                                const int* __restrict__ tarr) {
    __shared__ __align__(16) u16 ldsA[128 * 64];
    __shared__ __align__(16) u16 ldsB[128 * 64];

    const int bc = blockIdx.x;
    const int tsel = tarr[bc / 3];
    const u16* __restrict__ A = Pbf + (size_t)tsel * IMG * IMG;

    const int tile_m = (blockIdx.y >> 1) * 128;
    const int tile_n = (blockIdx.y & 1) * 128;
    const int tid = threadIdx.x;
    const int lane = tid & 63;
    const int wave = tid >> 6;
    const int wm = (wave >> 1) * 64;
    const int wn = (wave & 1) * 64;

    // Per-thread staging coords (invariant across q and kt):
    //   chunk id = q*256 + tid -> row = q*32 + (tid>>3), kb = tid&7
    //   swizzled chunk offset = (kb ^ (row&7))*8 ; row&7 == (tid>>3)&7
    const int tr = tid >> 3;
    const int kb = tid & 7;
    const int kswz = (kb ^ (tr & 7)) * 8;

    const u16* Arow = A + (size_t)(tile_m + tr) * IMG + kb * 8;
    const float* Xrow = (MODE == 0)
        ? (const float*)BtSrc + (size_t)bc * IMG * IMG + (size_t)(tile_n + tr) * IMG + kb * 8
        : nullptr;
    const u16* Zrow = (MODE == 1)
        ? (const u16*)BtSrc + (size_t)bc * IMG * IMG + (size_t)(tile_n + tr) * IMG + kb * 8
        : nullptr;

    uint4 rA[4];
    float4 rB0[4], rB1[4];  // MODE 0
    uint4 rBz[4];           // MODE 1

    // ---- fetch(kt): global -> regs (static q indices) ----
#define FETCH(kt)                                                              \
    {                                                                          \
        _Pragma("unroll") for (int q = 0; q < 4; ++q) {                        \
            rA[q] = *(const uint4*)(Arow + (size_t)(q * 32) * IMG + (kt) * 64);\
            if (MODE == 0) {                                                   \
                const float* xs = Xrow + (size_t)(q * 32) * IMG + (kt) * 64;   \
                rB0[q] = *(const float4*)(xs);                                 \
                rB1[q] = *(const float4*)(xs + 4);                             \
            } else {                                                           \
                rBz[q] = *(const uint4*)(Zrow + (size_t)(q * 32) * IMG + (kt) * 64); \
            }                                                                  \
        }                                                                      \
    }

    // ---- commit: regs -> LDS (waits vmcnt on the fetched regs) ----
#define COMMIT()                                                               \
    {                                                                          \
        _Pragma("unroll") for (int q = 0; q < 4; ++q) {                        \
            const int row = q * 32 + tr;                                       \
            *(uint4*)(ldsA + row * 64 + kswz) = rA[q];                         \
            if (MODE == 0) {                                                   \
                ushort8 pk;                                                    \
                pk[0] = f2bf(rB0[q].x); pk[1] = f2bf(rB0[q].y);                \
                pk[2] = f2bf(rB0[q].z); pk[3] = f2bf(rB0[q].w);                \
                pk[4] = f2bf(rB1[q].x); pk[5] = f2bf(rB1[q].y);                \
                pk[6] = f2bf(rB1[q].z); pk[7] = f2bf(rB1[q].w);                \
                *(ushort8*)(ldsB + row * 64 + kswz) = pk;                      \
            } else {                                                           \
                *(uint4*)(ldsB + row * 64 + kswz) = rBz[q];                    \
            }                                                                  \
        }                                                                      \
    }

    f32x4 acc[4][4];
#pragma unroll
    for (int i = 0; i < 4; ++i)
#pragma unroll
        for (int j = 0; j < 4; ++j) acc[i][j] = (f32x4){0.f, 0.f, 0.f, 0.f};

    FETCH(0);
#pragma unroll
    for (int kt = 0; kt < 4; ++kt) {
        __syncthreads();   // consumers of previous LDS tile done
        COMMIT();          // kt's data -> LDS
        if (kt < 3) FETCH(kt + 1);  // issue next loads; complete under MFMA
        __syncthreads();   // kt's LDS tile ready
#pragma unroll
        for (int kk = 0; kk < 2; ++kk) {
            const int ck = kk * 4 + (lane >> 4);
            bf16x8 afrag[4], bfrag[4];
#pragma unroll
            for (int mi = 0; mi < 4; ++mi) {
                const int r = wm + mi * 16 + (lane & 15);
                afrag[mi] = *(const bf16x8*)(ldsA + r * 64 + ((ck ^ (r & 7)) * 8));
            }
#pragma unroll
            for (int nj = 0; nj < 4; ++nj) {
                const int r = wn + nj * 16 + (lane & 15);
                bfrag[nj] = *(const bf16x8*)(ldsB + r * 64 + ((ck ^ (r & 7)) * 8));
            }
#pragma unroll
            for (int mi = 0; mi < 4; ++mi)
#pragma unroll
                for (int nj = 0; nj < 4; ++nj)
                    acc[mi][nj] = __builtin_amdgcn_mfma_f32_16x16x32_bf16(
                        afrag[mi], bfrag[nj], acc[mi][nj], 0, 0, 0);
        }
    }
#undef FETCH
#undef COMMIT

    const int col0 = lane & 15;
    const int row4 = (lane >> 4) * 4;
    if (MODE == 0) {
        u16* C = (u16*)Cout + (size_t)bc * IMG * IMG;
#pragma unroll
        for (int mi = 0; mi < 4; ++mi)
#pragma unroll
            for (int nj = 0; nj < 4; ++nj)
#pragma unroll
                for (int r = 0; r < 4; ++r) {
                    const int ro = tile_m + wm + mi * 16 + row4 + r;
                    const int co = tile_n + wn + nj * 16 + col0;
                    C[(size_t)ro * IMG + co] = f2bf(acc[mi][nj][r]);
                }
    } else {
        float* C = (float*)Cout + (size_t)bc * IMG * IMG;
#pragma unroll
        for (int mi = 0; mi < 4; ++mi)
#pragma unroll
            for (int nj = 0; nj < 4; ++nj)
#pragma unroll
                for (int r = 0; r < 4; ++r) {
                    const int ro = tile_m + wm + mi * 16 + row4 + r;
                    const int co = tile_n + wn + nj * 16 + col0;
                    C[(size_t)ro * IMG + co] = acc[mi][nj][r];
                }
    }
}

// ---------------------------------------------------------------------------
extern "C" void kernel_launch(void* const* d_in, const int* in_sizes, int n_in,
                              void* d_out, int out_size, void* d_ws, size_t ws_size,
                              hipStream_t stream) {
    const float* x0 = (const float*)d_in[0];
    const int* t = (const int*)d_in[1];
    float* out = (float*)d_out;

    // ws: P (20*256*256 bf16 = 2.62 MB) | Z (192*256*256 bf16 = 25.2 MB)
    u16* Pbf = (u16*)d_ws;
    u16* Z = (u16*)((char*)d_ws + (size_t)TS * IMG * IMG * sizeof(u16));

    hipLaunchKernelGGL(build_P2, dim3(IMG / BPC), dim3(IMG), 0, stream, Pbf);
    hipLaunchKernelGGL((gemm_px2<0>), dim3(192, 4), dim3(256), 0, stream,
                       Pbf, (const void*)x0, (void*)Z, t);
    hipLaunchKernelGGL((gemm_px2<1>), dim3(192, 4), dim3(256), 0, stream,
                       Pbf, (const void*)Z, (void*)out, t);
}

// Round 9
// 131.799 us; speedup vs baseline: 1.2529x; 1.2529x over previous
//
#include <hip/hip_runtime.h>
#include <hip/hip_bf16.h>

#define IMG 256
#define TS 20

typedef unsigned short u16;
typedef __bf16 bf16x8 __attribute__((ext_vector_type(8)));
typedef float f32x4 __attribute__((ext_vector_type(4)));
typedef unsigned short ushort8 __attribute__((ext_vector_type(8)));

__device__ __forceinline__ float cc1f(float x) {
    const float A = -0.75f;
    return ((A + 2.0f) * x - (A + 3.0f)) * x * x + 1.0f;
}
__device__ __forceinline__ float cc2f(float x) {
    const float A = -0.75f;
    return ((A * x - 5.0f * A) * x + 8.0f * A) * x - 4.0f * A;
}

// fp32 -> bf16 round-to-nearest-even, bit form
__device__ __forceinline__ u16 f2bf(float f) {
    unsigned u = __float_as_uint(f);
    u = u + 0x7fffu + ((u >> 16) & 1u);
    return (u16)(u >> 16);
}

// ---------------------------------------------------------------------------
// build_P2: P_0 = I; P_{i+1} = (N·B)_i · P_i  (row-gather, 4 nnz/row).
// Column-sliced: 32 blocks × 8 columns; 256 threads = one thread per row.
// (verified R4/R5, ~2-4 µs)
// ---------------------------------------------------------------------------
#define BPC 8
#define BPS 12
__global__ __launch_bounds__(256) void build_P2(u16* __restrict__ Pbf) {
    __shared__ __align__(16) float buf[2][IMG][BPS];
    const int col0 = blockIdx.x * BPC;
    const int o = threadIdx.x;

    f32x4 n0 = (f32x4){0.f, 0.f, 0.f, 0.f};
    f32x4 n1 = (f32x4){0.f, 0.f, 0.f, 0.f};
    if (o >= col0 && o < col0 + 4) n0[o - col0] = 1.0f;
    if (o >= col0 + 4 && o < col0 + 8) n1[o - col0 - 4] = 1.0f;
    *(f32x4*)&buf[0][o][0] = n0;
    *(f32x4*)&buf[0][o][4] = n1;
    {
        ushort8 pk;
#pragma unroll
        for (int c = 0; c < 4; ++c) pk[c] = f2bf(n0[c]);
#pragma unroll
        for (int c = 0; c < 4; ++c) pk[4 + c] = f2bf(n1[c]);
        *(ushort8*)(Pbf + (size_t)o * IMG + col0) = pk;
    }

    int cur = 0;
#pragma unroll
    for (int i = 0; i < TS - 1; ++i) {
        const int s = IMG - i;
        float xs = (o + 0.5f) * (float)s * (1.0f / 256.0f);
        int j = (int)xs;
        if (j > s - 1) j = s - 1;
        float x = (j + 0.5f) * (256.0f / (float)s) - 0.5f;
        float fl = floorf(x);
        int i0 = (int)fl;
        float tt = x - fl;
        float w[4] = {cc2f(tt + 1.0f), cc1f(tt), cc1f(1.0f - tt), cc2f(2.0f - tt)};
        int c[4];
#pragma unroll
        for (int k = 0; k < 4; ++k) c[k] = min(max(i0 - 1 + k, 0), IMG - 1);

        __syncthreads();
        f32x4 a0 = (f32x4){0.f, 0.f, 0.f, 0.f};
        f32x4 a1 = (f32x4){0.f, 0.f, 0.f, 0.f};
#pragma unroll
        for (int k = 0; k < 4; ++k) {
            const float wk = w[k];
            a0 += wk * *(const f32x4*)&buf[cur][c[k]][0];
            a1 += wk * *(const f32x4*)&buf[cur][c[k]][4];
        }
        const int nxt = cur ^ 1;
        *(f32x4*)&buf[nxt][o][0] = a0;
        *(f32x4*)&buf[nxt][o][4] = a1;

        ushort8 pk;
#pragma unroll
        for (int cc = 0; cc < 4; ++cc) pk[cc] = f2bf(a0[cc]);
#pragma unroll
        for (int cc = 0; cc < 4; ++cc) pk[4 + cc] = f2bf(a1[cc]);
        *(ushort8*)(Pbf + ((size_t)(i + 1) * IMG + o) * IMG + col0) = pk;
        cur = nxt;
    }
}

// ---------------------------------------------------------------------------
// gemm_px3: C[m,n] = sum_k A[m,k] * Bt[n,k], A = P[t[b]] (both modes).
// MODE 0 (gemm1): Bt = X[bc] fp32 (cvt on commit), C = Z[bc] bf16
// MODE 1 (gemm2): Bt = Z[bc] bf16,                 C = out[bc] fp32
// 128x128 tile, 4 waves x (64x64), BK=64, mfma_f32_16x16x32_bf16.
// T14 async-stage with NAMED scalar staging registers (rule #20: no
// runtime-indexed arrays -> no scratch). Fetch kt+1 issued before kt's MFMA
// phase; commit regs->LDS right after the barrier.
// ---------------------------------------------------------------------------
template <int MODE>
__global__ __launch_bounds__(256, 2) void gemm_px3(const u16* __restrict__ Pbf,
                                                   const void* __restrict__ BtSrc,
                                                   void* __restrict__ Cout,
                                                   const int* __restrict__ tarr) {
    __shared__ __align__(16) u16 ldsA[128 * 64];
    __shared__ __align__(16) u16 ldsB[128 * 64];

    const int bc = blockIdx.x;
    const int tsel = tarr[bc / 3];
    const u16* __restrict__ A = Pbf + (size_t)tsel * IMG * IMG;

    const int tile_m = (blockIdx.y >> 1) * 128;
    const int tile_n = (blockIdx.y & 1) * 128;
    const int tid = threadIdx.x;
    const int lane = tid & 63;
    const int wave = tid >> 6;
    const int wm = (wave >> 1) * 64;
    const int wn = (wave & 1) * 64;

    // Per-thread staging coords (invariant): chunk q covers row q*32+tr.
    const int tr = tid >> 3;   // 0..31
    const int kb = tid & 7;
    const int kswz = (kb ^ (tr & 7)) * 8;

    const u16* Arow = A + (size_t)(tile_m + tr) * IMG + kb * 8;
    const float* Xrow = (const float*)BtSrc + (size_t)bc * IMG * IMG +
                        (size_t)(tile_n + tr) * IMG + kb * 8;   // MODE 0
    const u16* Zrow = (const u16*)BtSrc + (size_t)bc * IMG * IMG +
                      (size_t)(tile_n + tr) * IMG + kb * 8;     // MODE 1

    // Named staging registers — NO arrays (rule #20).
    uint4 a0, a1, a2, a3;
    float4 x0a, x0b, x1a, x1b, x2a, x2b, x3a, x3b;
    uint4 z0, z1, z2, z3;

#define LDA(q, kt) (*(const uint4*)(Arow + (size_t)((q) * 32) * IMG + (kt) * 64))
#define LDX(q, kt, hf) (*(const float4*)(Xrow + (size_t)((q) * 32) * IMG + (kt) * 64 + (hf) * 4))
#define LDZ(q, kt) (*(const uint4*)(Zrow + (size_t)((q) * 32) * IMG + (kt) * 64))

#define FETCH(kt)                                                       \
    do {                                                                \
        a0 = LDA(0, kt); a1 = LDA(1, kt); a2 = LDA(2, kt); a3 = LDA(3, kt); \
        if (MODE == 0) {                                                \
            x0a = LDX(0, kt, 0); x0b = LDX(0, kt, 1);                   \
            x1a = LDX(1, kt, 0); x1b = LDX(1, kt, 1);                   \
            x2a = LDX(2, kt, 0); x2b = LDX(2, kt, 1);                   \
            x3a = LDX(3, kt, 0); x3b = LDX(3, kt, 1);                   \
        } else {                                                        \
            z0 = LDZ(0, kt); z1 = LDZ(1, kt); z2 = LDZ(2, kt); z3 = LDZ(3, kt); \
        }                                                               \
    } while (0)

#define ST_A(q, reg) *(uint4*)(ldsA + ((q) * 32 + tr) * 64 + kswz) = (reg)
#define ST_BX(q, va, vb)                                                \
    do {                                                                \
        ushort8 pk;                                                     \
        pk[0] = f2bf((va).x); pk[1] = f2bf((va).y);                     \
        pk[2] = f2bf((va).z); pk[3] = f2bf((va).w);                     \
        pk[4] = f2bf((vb).x); pk[5] = f2bf((vb).y);                     \
        pk[6] = f2bf((vb).z); pk[7] = f2bf((vb).w);                     \
        *(ushort8*)(ldsB + ((q) * 32 + tr) * 64 + kswz) = pk;           \
    } while (0)
#define ST_BZ(q, reg) *(uint4*)(ldsB + ((q) * 32 + tr) * 64 + kswz) = (reg)

#define COMMIT()                                                        \
    do {                                                                \
        ST_A(0, a0); ST_A(1, a1); ST_A(2, a2); ST_A(3, a3);             \
        if (MODE == 0) {                                                \
            ST_BX(0, x0a, x0b); ST_BX(1, x1a, x1b);                     \
            ST_BX(2, x2a, x2b); ST_BX(3, x3a, x3b);                     \
        } else {                                                        \
            ST_BZ(0, z0); ST_BZ(1, z1); ST_BZ(2, z2); ST_BZ(3, z3);     \
        }                                                               \
    } while (0)

    f32x4 acc[4][4];
#pragma unroll
    for (int i = 0; i < 4; ++i)
#pragma unroll
        for (int j = 0; j < 4; ++j) acc[i][j] = (f32x4){0.f, 0.f, 0.f, 0.f};

    FETCH(0);
#pragma unroll
    for (int kt = 0; kt < 4; ++kt) {
        __syncthreads();            // previous tile's consumers done
        COMMIT();                   // kt's data -> LDS (SSA: compiler renames)
        if (kt < 3) FETCH(kt + 1);  // next loads complete under MFMA
        __syncthreads();            // kt's LDS tile ready
#pragma unroll
        for (int kk = 0; kk < 2; ++kk) {
            const int ck = kk * 4 + (lane >> 4);
            bf16x8 afrag[4], bfrag[4];
#pragma unroll
            for (int mi = 0; mi < 4; ++mi) {
                const int r = wm + mi * 16 + (lane & 15);
                afrag[mi] = *(const bf16x8*)(ldsA + r * 64 + ((ck ^ (r & 7)) * 8));
            }
#pragma unroll
            for (int nj = 0; nj < 4; ++nj) {
                const int r = wn + nj * 16 + (lane & 15);
                bfrag[nj] = *(const bf16x8*)(ldsB + r * 64 + ((ck ^ (r & 7)) * 8));
            }
#pragma unroll
            for (int mi = 0; mi < 4; ++mi)
#pragma unroll
                for (int nj = 0; nj < 4; ++nj)
                    acc[mi][nj] = __builtin_amdgcn_mfma_f32_16x16x32_bf16(
                        afrag[mi], bfrag[nj], acc[mi][nj], 0, 0, 0);
        }
    }
#undef FETCH
#undef COMMIT
#undef LDA
#undef LDX
#undef LDZ
#undef ST_A
#undef ST_BX
#undef ST_BZ

    const int col0 = lane & 15;
    const int row4 = (lane >> 4) * 4;
    if (MODE == 0) {
        u16* C = (u16*)Cout + (size_t)bc * IMG * IMG;
#pragma unroll
        for (int mi = 0; mi < 4; ++mi)
#pragma unroll
            for (int nj = 0; nj < 4; ++nj)
#pragma unroll
                for (int r = 0; r < 4; ++r) {
                    const int ro = tile_m + wm + mi * 16 + row4 + r;
                    const int co = tile_n + wn + nj * 16 + col0;
                    C[(size_t)ro * IMG + co] = f2bf(acc[mi][nj][r]);
                }
    } else {
        float* C = (float*)Cout + (size_t)bc * IMG * IMG;
#pragma unroll
        for (int mi = 0; mi < 4; ++mi)
#pragma unroll
            for (int nj = 0; nj < 4; ++nj)
#pragma unroll
                for (int r = 0; r < 4; ++r) {
                    const int ro = tile_m + wm + mi * 16 + row4 + r;
                    const int co = tile_n + wn + nj * 16 + col0;
                    C[(size_t)ro * IMG + co] = acc[mi][nj][r];
                }
    }
}

// ---------------------------------------------------------------------------
extern "C" void kernel_launch(void* const* d_in, const int* in_sizes, int n_in,
                              void* d_out, int out_size, void* d_ws, size_t ws_size,
                              hipStream_t stream) {
    const float* x0 = (const float*)d_in[0];
    const int* t = (const int*)d_in[1];
    float* out = (float*)d_out;

    // ws: P (20*256*256 bf16 = 2.62 MB) | Z (192*256*256 bf16 = 25.2 MB)
    u16* Pbf = (u16*)d_ws;
    u16* Z = (u16*)((char*)d_ws + (size_t)TS * IMG * IMG * sizeof(u16));

    hipLaunchKernelGGL(build_P2, dim3(IMG / BPC), dim3(IMG), 0, stream, Pbf);
    hipLaunchKernelGGL((gemm_px3<0>), dim3(192, 4), dim3(256), 0, stream,
                       Pbf, (const void*)x0, (void*)Z, t);
    hipLaunchKernelGGL((gemm_px3<1>), dim3(192, 4), dim3(256), 0, stream,
                       Pbf, (const void*)Z, (void*)out, t);
}

// Round 12
// 131.082 us; speedup vs baseline: 1.2597x; 1.0055x over previous
//
#include <hip/hip_runtime.h>
#include <hip/hip_bf16.h>

#define IMG 256
#define TS 20

typedef unsigned short u16;
typedef __bf16 bf16x8 __attribute__((ext_vector_type(8)));
typedef float f32x4 __attribute__((ext_vector_type(4)));
typedef unsigned short ushort8 __attribute__((ext_vector_type(8)));

__device__ __forceinline__ float cc1f(float x) {
    const float A = -0.75f;
    return ((A + 2.0f) * x - (A + 3.0f)) * x * x + 1.0f;
}
__device__ __forceinline__ float cc2f(float x) {
    const float A = -0.75f;
    return ((A * x - 5.0f * A) * x + 8.0f * A) * x - 4.0f * A;
}

// fp32 -> bf16 round-to-nearest-even, bit form
__device__ __forceinline__ u16 f2bf(float f) {
    unsigned u = __float_as_uint(f);
    u = u + 0x7fffu + ((u >> 16) & 1u);
    return (u16)(u >> 16);
}

// ---------------------------------------------------------------------------
// build_P2: P_0 = I; P_{i+1} = (N·B)_i · P_i  (row-gather, 4 nnz/row).
// (verified R4-R9, ~2-4 µs)
// ---------------------------------------------------------------------------
#define BPC 8
#define BPS 12
__global__ __launch_bounds__(256) void build_P2(u16* __restrict__ Pbf) {
    __shared__ __align__(16) float buf[2][IMG][BPS];
    const int col0 = blockIdx.x * BPC;
    const int o = threadIdx.x;

    f32x4 n0 = (f32x4){0.f, 0.f, 0.f, 0.f};
    f32x4 n1 = (f32x4){0.f, 0.f, 0.f, 0.f};
    if (o >= col0 && o < col0 + 4) n0[o - col0] = 1.0f;
    if (o >= col0 + 4 && o < col0 + 8) n1[o - col0 - 4] = 1.0f;
    *(f32x4*)&buf[0][o][0] = n0;
    *(f32x4*)&buf[0][o][4] = n1;
    {
        ushort8 pk;
#pragma unroll
        for (int c = 0; c < 4; ++c) pk[c] = f2bf(n0[c]);
#pragma unroll
        for (int c = 0; c < 4; ++c) pk[4 + c] = f2bf(n1[c]);
        *(ushort8*)(Pbf + (size_t)o * IMG + col0) = pk;
    }

    int cur = 0;
#pragma unroll
    for (int i = 0; i < TS - 1; ++i) {
        const int s = IMG - i;
        float xs = (o + 0.5f) * (float)s * (1.0f / 256.0f);
        int j = (int)xs;
        if (j > s - 1) j = s - 1;
        float x = (j + 0.5f) * (256.0f / (float)s) - 0.5f;
        float fl = floorf(x);
        int i0 = (int)fl;
        float tt = x - fl;
        float w[4] = {cc2f(tt + 1.0f), cc1f(tt), cc1f(1.0f - tt), cc2f(2.0f - tt)};
        int c[4];
#pragma unroll
        for (int k = 0; k < 4; ++k) c[k] = min(max(i0 - 1 + k, 0), IMG - 1);

        __syncthreads();
        f32x4 a0 = (f32x4){0.f, 0.f, 0.f, 0.f};
        f32x4 a1 = (f32x4){0.f, 0.f, 0.f, 0.f};
#pragma unroll
        for (int k = 0; k < 4; ++k) {
            const float wk = w[k];
            a0 += wk * *(const f32x4*)&buf[cur][c[k]][0];
            a1 += wk * *(const f32x4*)&buf[cur][c[k]][4];
        }
        const int nxt = cur ^ 1;
        *(f32x4*)&buf[nxt][o][0] = a0;
        *(f32x4*)&buf[nxt][o][4] = a1;

        ushort8 pk;
#pragma unroll
        for (int cc = 0; cc < 4; ++cc) pk[cc] = f2bf(a0[cc]);
#pragma unroll
        for (int cc = 0; cc < 4; ++cc) pk[4 + cc] = f2bf(a1[cc]);
        *(ushort8*)(Pbf + ((size_t)(i + 1) * IMG + o) * IMG + col0) = pk;
        cur = nxt;
    }
}

// ---------------------------------------------------------------------------
// gemm_px4: C[m,n] = sum_k A[m,k] * Bt[n,k], A = P[t[b]] (both modes).
// MODE 0 (gemm1): Bt = X[bc] fp32 (cvt on commit), C = Z[bc] bf16
// MODE 1 (gemm2): Bt = Z[bc] bf16,                 C = out[bc] fp32
// OCCUPANCY RETILE: 128x64 tile, 4 waves x (64x32), BK=64.
// acc = 32 f32/thread -> VGPR ~110 -> 4 waves/SIMD; LDS 24 KB -> 4 blocks/CU
// -> 16 waves/CU. 1536 blocks. T14 named-reg staging.
// grid(8,192): the 8 tiles of one image adjacent in dispatch order.
// ---------------------------------------------------------------------------
template <int MODE>
__global__ __launch_bounds__(256, 4) void gemm_px4(const u16* __restrict__ Pbf,
                                                   const void* __restrict__ BtSrc,
                                                   void* __restrict__ Cout,
                                                   const int* __restrict__ tarr) {
    __shared__ __align__(16) u16 ldsA[128 * 64];  // 16 KB
    __shared__ __align__(16) u16 ldsB[64 * 64];   //  8 KB

    const int bc = blockIdx.y;
    const int tsel = tarr[bc / 3];
    const u16* __restrict__ A = Pbf + (size_t)tsel * IMG * IMG;

    const int tile_m = (blockIdx.x >> 2) * 128;   // 2 m-tiles
    const int tile_n = (blockIdx.x & 3) * 64;     // 4 n-tiles
    const int tid = threadIdx.x;
    const int lane = tid & 63;
    const int wave = tid >> 6;
    const int wm = (wave >> 1) * 64;              // 0 / 64
    const int wn = (wave & 1) * 32;               // 0 / 32

    // staging coords: A chunk q covers row q*32+tr; B chunk s covers row s*32+tr
    const int tr = tid >> 3;   // 0..31
    const int kb = tid & 7;
    const int kswz = (kb ^ (tr & 7)) * 8;

    const u16* Arow = A + (size_t)(tile_m + tr) * IMG + kb * 8;
    const float* Xrow = (const float*)BtSrc + (size_t)bc * IMG * IMG +
                        (size_t)(tile_n + tr) * IMG + kb * 8;   // MODE 0
    const u16* Zrow = (const u16*)BtSrc + (size_t)bc * IMG * IMG +
                      (size_t)(tile_n + tr) * IMG + kb * 8;     // MODE 1

    // Named staging registers (rule #20: no runtime-indexed arrays).
    uint4 a0, a1, a2, a3;
    float4 x0a, x0b, x1a, x1b;
    uint4 z0, z1;

#define LDA(q, kt) (*(const uint4*)(Arow + (size_t)((q) * 32) * IMG + (kt) * 64))
#define LDX(s, kt, hf) (*(const float4*)(Xrow + (size_t)((s) * 32) * IMG + (kt) * 64 + (hf) * 4))
#define LDZ(s, kt) (*(const uint4*)(Zrow + (size_t)((s) * 32) * IMG + (kt) * 64))

#define FETCH(kt)                                                       \
    do {                                                                \
        a0 = LDA(0, kt); a1 = LDA(1, kt); a2 = LDA(2, kt); a3 = LDA(3, kt); \
        if (MODE == 0) {                                                \
            x0a = LDX(0, kt, 0); x0b = LDX(0, kt, 1);                   \
            x1a = LDX(1, kt, 0); x1b = LDX(1, kt, 1);                   \
        } else {                                                        \
            z0 = LDZ(0, kt); z1 = LDZ(1, kt);                           \
        }                                                               \
    } while (0)

#define ST_A(q, reg) *(uint4*)(ldsA + ((q) * 32 + tr) * 64 + kswz) = (reg)
#define ST_BX(s, va, vb)                                                \
    do {                                                                \
        ushort8 pk;                                                     \
        pk[0] = f2bf((va).x); pk[1] = f2bf((va).y);                     \
        pk[2] = f2bf((va).z); pk[3] = f2bf((va).w);                     \
        pk[4] = f2bf((vb).x); pk[5] = f2bf((vb).y);                     \
        pk[6] = f2bf((vb).z); pk[7] = f2bf((vb).w);                     \
        *(ushort8*)(ldsB + ((s) * 32 + tr) * 64 + kswz) = pk;           \
    } while (0)
#define ST_BZ(s, reg) *(uint4*)(ldsB + ((s) * 32 + tr) * 64 + kswz) = (reg)

#define COMMIT()                                                        \
    do {                                                                \
        ST_A(0, a0); ST_A(1, a1); ST_A(2, a2); ST_A(3, a3);             \
        if (MODE == 0) { ST_BX(0, x0a, x0b); ST_BX(1, x1a, x1b); }      \
        else           { ST_BZ(0, z0); ST_BZ(1, z1); }                  \
    } while (0)

    f32x4 acc[4][2];
#pragma unroll
    for (int i = 0; i < 4; ++i)
#pragma unroll
        for (int j = 0; j < 2; ++j) acc[i][j] = (f32x4){0.f, 0.f, 0.f, 0.f};

    FETCH(0);
#pragma unroll
    for (int kt = 0; kt < 4; ++kt) {
        __syncthreads();            // previous tile's consumers done
        COMMIT();                   // kt's data -> LDS
        if (kt < 3) FETCH(kt + 1);  // next loads complete under MFMA
        __syncthreads();            // kt's LDS tile ready
#pragma unroll
        for (int kk = 0; kk < 2; ++kk) {
            const int ck = kk * 4 + (lane >> 4);
            bf16x8 afrag[4], bfrag[2];
#pragma unroll
            for (int mi = 0; mi < 4; ++mi) {
                const int r = wm + mi * 16 + (lane & 15);
                afrag[mi] = *(const bf16x8*)(ldsA + r * 64 + ((ck ^ (r & 7)) * 8));
            }
#pragma unroll
            for (int nj = 0; nj < 2; ++nj) {
                const int r = wn + nj * 16 + (lane & 15);
                bfrag[nj] = *(const bf16x8*)(ldsB + r * 64 + ((ck ^ (r & 7)) * 8));
            }
#pragma unroll
            for (int mi = 0; mi < 4; ++mi)
#pragma unroll
                for (int nj = 0; nj < 2; ++nj)
                    acc[mi][nj] = __builtin_amdgcn_mfma_f32_16x16x32_bf16(
                        afrag[mi], bfrag[nj], acc[mi][nj], 0, 0, 0);
        }
    }
#undef FETCH
#undef COMMIT
#undef LDA
#undef LDX
#undef LDZ
#undef ST_A
#undef ST_BX
#undef ST_BZ

    const int col0 = lane & 15;
    const int row4 = (lane >> 4) * 4;
    if (MODE == 0) {
        u16* C = (u16*)Cout + (size_t)bc * IMG * IMG;
#pragma unroll
        for (int mi = 0; mi < 4; ++mi)
#pragma unroll
            for (int nj = 0; nj < 2; ++nj)
#pragma unroll
                for (int r = 0; r < 4; ++r) {
                    const int ro = tile_m + wm + mi * 16 + row4 + r;
                    const int co = tile_n + wn + nj * 16 + col0;
                    C[(size_t)ro * IMG + co] = f2bf(acc[mi][nj][r]);
                }
    } else {
        float* C = (float*)Cout + (size_t)bc * IMG * IMG;
#pragma unroll
        for (int mi = 0; mi < 4; ++mi)
#pragma unroll
            for (int nj = 0; nj < 2; ++nj)
#pragma unroll
                for (int r = 0; r < 4; ++r) {
                    const int ro = tile_m + wm + mi * 16 + row4 + r;
                    const int co = tile_n + wn + nj * 16 + col0;
                    C[(size_t)ro * IMG + co] = acc[mi][nj][r];
                }
    }
}

// ---------------------------------------------------------------------------
extern "C" void kernel_launch(void* const* d_in, const int* in_sizes, int n_in,
                              void* d_out, int out_size, void* d_ws, size_t ws_size,
                              hipStream_t stream) {
    const float* x0 = (const float*)d_in[0];
    const int* t = (const int*)d_in[1];
    float* out = (float*)d_out;

    // ws: P (20*256*256 bf16 = 2.62 MB) | Z (192*256*256 bf16 = 25.2 MB)
    u16* Pbf = (u16*)d_ws;
    u16* Z = (u16*)((char*)d_ws + (size_t)TS * IMG * IMG * sizeof(u16));

    hipLaunchKernelGGL(build_P2, dim3(IMG / BPC), dim3(IMG), 0, stream, Pbf);
    hipLaunchKernelGGL((gemm_px4<0>), dim3(8, 192), dim3(256), 0, stream,
                       Pbf, (const void*)x0, (void*)Z, t);
    hipLaunchKernelGGL((gemm_px4<1>), dim3(8, 192), dim3(256), 0, stream,
                       Pbf, (const void*)Z, (void*)out, t);
}